// Round 2
// baseline (976.788 us; speedup 1.0000x reference)
//
#include <hip/hip_runtime.h>
#include <hip/hip_bf16.h>
#include <math.h>

// MoE FFN: N=8192 tokens, C=1024, H=4096, E=8, TOP_K=2.
// Round 4: 256x256xBK64 GEMM blocks, 8 waves (2Mx4N), 128 KiB double-buffered
// LDS, counted-vmcnt pipeline (s_waitcnt vmcnt(8), never 0 in main loop),
// raw s_barrier (no implicit vmcnt drain), s_setprio around MFMA clusters,
// involutive XOR swizzle (8-chunk rows) for conflict-free ds_read_b128,
// XCD-aware bijective block swizzle, fc2 2-way K-split for load balance.

#define N_TOK   8192
#define C_DIM   1024
#define H_DIM   4096
#define N_EXP   8
#define CAP     8192

typedef __bf16 bf16;
typedef bf16  bf16x8 __attribute__((ext_vector_type(8)));
typedef float f32x4  __attribute__((ext_vector_type(4)));

__device__ __forceinline__ void async_ld16(const void* g, void* l) {
    __builtin_amdgcn_global_load_lds(
        (const __attribute__((address_space(1))) void*)g,
        (__attribute__((address_space(3))) void*)l,
        16, 0, 0);
}

__device__ __forceinline__ float gelu_f(float v) {
    float u = v + 0.044715f * v * v * v;
    return 0.5f * v * (1.0f + tanhf(0.7978845608028654f * u));
}

// ---------------- fp32 -> bf16 for x, w1, w2 in one launch ----------------
#define NX8 ((size_t)N_TOK * C_DIM / 8)
#define NW8 ((size_t)N_EXP * H_DIM * C_DIM / 8)
#define NCVT (NX8 + 2 * NW8)

__global__ __launch_bounds__(256) void cvt_all_k(const float* __restrict__ x,
                                                 const float* __restrict__ w1,
                                                 const float* __restrict__ w2,
                                                 bf16* __restrict__ xb,
                                                 bf16* __restrict__ w1b,
                                                 bf16* __restrict__ w2b) {
    size_t i = (size_t)blockIdx.x * 256 + threadIdx.x;
    if (i >= NCVT) return;
    const float* src; bf16* dst; size_t j;
    if (i < NX8)            { src = x;  dst = xb;  j = i; }
    else if (i < NX8 + NW8) { src = w1; dst = w1b; j = i - NX8; }
    else                    { src = w2; dst = w2b; j = i - NX8 - NW8; }
    const float4* p = (const float4*)src + j * 2;
    float4 a = p[0], b = p[1];
    bf16x8 v;
    v[0] = (bf16)a.x; v[1] = (bf16)a.y; v[2] = (bf16)a.z; v[3] = (bf16)a.w;
    v[4] = (bf16)b.x; v[5] = (bf16)b.y; v[6] = (bf16)b.z; v[7] = (bf16)b.w;
    *((bf16x8*)dst + j) = v;
}

// ---------------- router ----------------
__global__ __launch_bounds__(1024) void router_k(const float* __restrict__ x,
                                                 const float* __restrict__ rw,
                                                 int* __restrict__ counts,
                                                 int* __restrict__ tok,
                                                 float* __restrict__ gate) {
    __shared__ int lcnt[N_EXP];
    __shared__ int lbase[N_EXP];
    const int tid  = threadIdx.x;
    const int lane = tid & 63;
    const int wv   = tid >> 6;
    if (tid < N_EXP) lcnt[tid] = 0;
    __syncthreads();

    const int t = blockIdx.x * 16 + wv;

    float dot[N_EXP];
#pragma unroll
    for (int e = 0; e < N_EXP; ++e) dot[e] = 0.f;
    const float4* xr = (const float4*)(x + (size_t)t * C_DIM);
#pragma unroll
    for (int j = 0; j < 4; ++j) {
        float4 xv = xr[j * 64 + lane];
#pragma unroll
        for (int e = 0; e < N_EXP; ++e) {
            float4 w4 = ((const float4*)(rw + (size_t)e * C_DIM))[j * 64 + lane];
            dot[e] += xv.x * w4.x + xv.y * w4.y + xv.z * w4.z + xv.w * w4.w;
        }
    }
#pragma unroll
    for (int e = 0; e < N_EXP; ++e) {
#pragma unroll
        for (int o = 32; o > 0; o >>= 1) dot[e] += __shfl_xor(dot[e], o, 64);
    }

    int a = 0, b = 0, ra = 0, rb = 0;
    float g0 = 0.f, g1 = 0.f;
    if (lane == 0) {
        float m = dot[0];
#pragma unroll
        for (int e = 1; e < N_EXP; ++e) m = fmaxf(m, dot[e]);
        float p[N_EXP]; float s = 0.f;
#pragma unroll
        for (int e = 0; e < N_EXP; ++e) { p[e] = expf(dot[e] - m); s += p[e]; }
        a = 0;
#pragma unroll
        for (int e = 1; e < N_EXP; ++e) if (p[e] > p[a]) a = e;
        b = -1;
#pragma unroll
        for (int e = 0; e < N_EXP; ++e) if (e != a && (b < 0 || p[e] > p[b])) b = e;
        float pa = p[a] / s, pb = p[b] / s;
        float d = pa + pb + 1e-8f;
        g0 = pa / d; g1 = pb / d;
        ra = atomicAdd(&lcnt[a], 1);
        rb = atomicAdd(&lcnt[b], 1);
    }
    __syncthreads();
    if (tid < N_EXP) lbase[tid] = atomicAdd(&counts[tid], lcnt[tid]);
    __syncthreads();
    if (lane == 0) {
        int sa = lbase[a] + ra;
        int sb = lbase[b] + rb;
        tok[a * CAP + sa] = t;  gate[a * CAP + sa] = g0;
        tok[b * CAP + sb] = t;  gate[b * CAP + sb] = g1;
    }
}

// LDS swizzle (BK=64, 128B rows = 8 chunks of 16B): LDS chunk (row,c) holds
// global chunk c ^ (row&7). Stage: lane tid loads global chunk
// (tid&7)^((tid>>3)&7), writes LDS linearly (wave-uniform base + lane*16 ✓).
// Read: global chunk q=kk*4+g -> LDS chunk q^(r&7); every 8 consecutive lanes
// of a ds_read_b128 cover all 8 chunk positions = all 32 banks.

// ---------------- fc1: h = gelu(x_gathered @ w1^T + b1) ----------------
__global__ __launch_bounds__(512, 2) void fc1_k(const bf16* __restrict__ xb,
                                                const bf16* __restrict__ w1b,
                                                const float* __restrict__ b1,
                                                const int* __restrict__ counts,
                                                const int* __restrict__ tok,
                                                bf16* __restrict__ h) {
    // XCD swizzle: nwg = 16*32*8 = 4096 (%8==0 -> bijective)
    const int lin = blockIdx.x + 16 * (blockIdx.y + 32 * blockIdx.z);
    const int w   = (lin & 7) * 512 + (lin >> 3);
    const int by  = w & 31;
    const int bx  = (w >> 5) & 15;
    const int e   = w >> 9;

    const int cnt = counts[e];
    const int m0  = by * 256;
    if (m0 >= cnt) return;
    const int n0  = bx * 256;

    int off = 0;
    for (int j = 0; j < e; ++j) off += counts[j];

    __shared__ __align__(16) bf16 As[2][256][64];   // 64 KiB
    __shared__ __align__(16) bf16 Bs[2][256][64];   // 64 KiB

    const int tid  = threadIdx.x;
    const int lane = tid & 63;
    const int wv   = tid >> 6;
    const int wm   = wv >> 2;        // 0..1 : rows wm*128..+127
    const int wn   = wv & 3;         // 0..3 : cols wn*64..+63
    const int r_   = lane & 15;
    const int g_   = lane >> 4;      // 0..3
    const int r7   = r_ & 7;

    const int row8 = tid >> 3;       // 0..63
    const int col8 = (tid & 7) * 8;
    const int scol = (((tid & 7) ^ ((tid >> 3) & 7))) * 8;

    const bf16* pA[4]; const bf16* pB[4];
#pragma unroll
    for (int j = 0; j < 4; ++j) {
        const int rr = j * 64 + row8;
        const int i  = m0 + rr;
        const int tk = tok[e * CAP + (i < cnt ? i : cnt - 1)];
        pA[j] = xb + (size_t)tk * C_DIM + scol;
        pB[j] = w1b + ((size_t)e * H_DIM + n0 + rr) * C_DIM + scol;
    }

    f32x4 acc[8][4];
#pragma unroll
    for (int mi = 0; mi < 8; ++mi)
#pragma unroll
        for (int ni = 0; ni < 4; ++ni)
#pragma unroll
            for (int r = 0; r < 4; ++r) acc[mi][ni][r] = 0.f;

#define STAGE1(buf, kt) do {                                              \
    async_ld16(pA[0] + (kt) * 64, &As[buf][  0 + row8][col8]);            \
    async_ld16(pB[0] + (kt) * 64, &Bs[buf][  0 + row8][col8]);            \
    async_ld16(pA[1] + (kt) * 64, &As[buf][ 64 + row8][col8]);            \
    async_ld16(pB[1] + (kt) * 64, &Bs[buf][ 64 + row8][col8]);            \
    async_ld16(pA[2] + (kt) * 64, &As[buf][128 + row8][col8]);            \
    async_ld16(pB[2] + (kt) * 64, &Bs[buf][128 + row8][col8]);            \
    async_ld16(pA[3] + (kt) * 64, &As[buf][192 + row8][col8]);            \
    async_ld16(pB[3] + (kt) * 64, &Bs[buf][192 + row8][col8]); } while (0)

    STAGE1(0, 0);
    STAGE1(1, 1);
    asm volatile("s_waitcnt vmcnt(8)" ::: "memory");   // tile 0 landed
    __builtin_amdgcn_sched_barrier(0);
    __builtin_amdgcn_s_barrier();

    for (int t = 0; t < C_DIM / 64; ++t) {
        const int cur = t & 1;
        bf16x8 bfr[4][2];
#pragma unroll
        for (int ni = 0; ni < 4; ++ni)
#pragma unroll
            for (int kk = 0; kk < 2; ++kk)
                bfr[ni][kk] = *(const bf16x8*)&Bs[cur][wn * 64 + ni * 16 + r_][((kk * 4 + g_) ^ r7) * 8];

#pragma unroll
        for (int half = 0; half < 2; ++half) {
            bf16x8 afr[4][2];
#pragma unroll
            for (int mi = 0; mi < 4; ++mi)
#pragma unroll
                for (int kk = 0; kk < 2; ++kk)
                    afr[mi][kk] = *(const bf16x8*)&As[cur][wm * 128 + (half * 4 + mi) * 16 + r_][((kk * 4 + g_) ^ r7) * 8];
            __builtin_amdgcn_s_setprio(1);
#pragma unroll
            for (int kk = 0; kk < 2; ++kk)
#pragma unroll
                for (int ni = 0; ni < 4; ++ni)
#pragma unroll
                    for (int mi = 0; mi < 4; ++mi)
                        acc[half * 4 + mi][ni] = __builtin_amdgcn_mfma_f32_16x16x32_bf16(
                            afr[mi][kk], bfr[ni][kk], acc[half * 4 + mi][ni], 0, 0, 0);
            __builtin_amdgcn_s_setprio(0);
        }
        asm volatile("s_waitcnt lgkmcnt(0)" ::: "memory");  // own reads of buf cur done
        __builtin_amdgcn_sched_barrier(0);
        __builtin_amdgcn_s_barrier();                        // ALL waves done reading buf cur
        if (t + 2 < C_DIM / 64) {
            STAGE1(cur, t + 2);                              // overwrite buf cur
            asm volatile("s_waitcnt vmcnt(8)" ::: "memory"); // tile t+1 landed (own)
        } else {
            asm volatile("s_waitcnt vmcnt(0)" ::: "memory");
        }
        __builtin_amdgcn_sched_barrier(0);
        __builtin_amdgcn_s_barrier();                        // tile t+1 landed (all)
    }
#undef STAGE1

    float bias[4];
#pragma unroll
    for (int ni = 0; ni < 4; ++ni)
        bias[ni] = b1[(size_t)e * H_DIM + n0 + wn * 64 + ni * 16 + r_];

    const int lg = lane >> 4;
#pragma unroll
    for (int mi = 0; mi < 8; ++mi) {
#pragma unroll
        for (int r = 0; r < 4; ++r) {
            const int m = wm * 128 + mi * 16 + lg * 4 + r;
            if (m0 + m < cnt) {
                const size_t hrow = (size_t)(off + m0 + m) * H_DIM;
#pragma unroll
                for (int ni = 0; ni < 4; ++ni) {
                    const int n = n0 + wn * 64 + ni * 16 + r_;
                    h[hrow + n] = (bf16)gelu_f(acc[mi][ni][r] + bias[ni]);
                }
            }
        }
    }
}

// ---------------- fc2: out += gate * (h @ w2^T + b2), 2-way K-split ----------------
__global__ __launch_bounds__(512, 2) void fc2_k(const bf16* __restrict__ h,
                                                const bf16* __restrict__ w2b,
                                                const float* __restrict__ b2,
                                                const int* __restrict__ counts,
                                                const int* __restrict__ tok,
                                                const float* __restrict__ gate,
                                                float* __restrict__ out) {
    // XCD swizzle: nwg = 4*32*16 = 2048 (%8==0 -> bijective)
    const int lin = blockIdx.x + 4 * (blockIdx.y + 32 * blockIdx.z);
    const int w   = (lin & 7) * 256 + (lin >> 3);
    const int by  = w & 31;
    const int bx  = (w >> 5) & 3;
    const int e   = (w >> 7) & 7;
    const int ks  = w >> 10;                 // K-split half: kt in [ks*32, ks*32+32)

    const int cnt = counts[e];
    const int m0  = by * 256;
    if (m0 >= cnt) return;
    const int n0  = bx * 256;

    int off = 0;
    for (int j = 0; j < e; ++j) off += counts[j];

    __shared__ __align__(16) bf16 As[2][256][64];
    __shared__ __align__(16) bf16 Bs[2][256][64];

    const int tid  = threadIdx.x;
    const int lane = tid & 63;
    const int wv   = tid >> 6;
    const int wm   = wv >> 2;
    const int wn   = wv & 3;
    const int r_   = lane & 15;
    const int g_   = lane >> 4;
    const int r7   = r_ & 7;

    const int row8 = tid >> 3;
    const int col8 = (tid & 7) * 8;
    const int scol = (((tid & 7) ^ ((tid >> 3) & 7))) * 8;

    const bf16* pA[4]; const bf16* pB[4];
#pragma unroll
    for (int j = 0; j < 4; ++j) {
        const int rr = j * 64 + row8;
        const int i  = m0 + rr;
        pA[j] = h + (size_t)(off + (i < cnt ? i : cnt - 1)) * H_DIM + (size_t)ks * 2048 + scol;
        pB[j] = w2b + ((size_t)e * C_DIM + n0 + rr) * H_DIM + (size_t)ks * 2048 + scol;
    }

    f32x4 acc[8][4];
#pragma unroll
    for (int mi = 0; mi < 8; ++mi)
#pragma unroll
        for (int ni = 0; ni < 4; ++ni)
#pragma unroll
            for (int r = 0; r < 4; ++r) acc[mi][ni][r] = 0.f;

#define STAGE2(buf, kt) do {                                              \
    async_ld16(pA[0] + (kt) * 64, &As[buf][  0 + row8][col8]);            \
    async_ld16(pB[0] + (kt) * 64, &Bs[buf][  0 + row8][col8]);            \
    async_ld16(pA[1] + (kt) * 64, &As[buf][ 64 + row8][col8]);            \
    async_ld16(pB[1] + (kt) * 64, &Bs[buf][ 64 + row8][col8]);            \
    async_ld16(pA[2] + (kt) * 64, &As[buf][128 + row8][col8]);            \
    async_ld16(pB[2] + (kt) * 64, &Bs[buf][128 + row8][col8]);            \
    async_ld16(pA[3] + (kt) * 64, &As[buf][192 + row8][col8]);            \
    async_ld16(pB[3] + (kt) * 64, &Bs[buf][192 + row8][col8]); } while (0)

    STAGE2(0, 0);
    STAGE2(1, 1);
    asm volatile("s_waitcnt vmcnt(8)" ::: "memory");
    __builtin_amdgcn_sched_barrier(0);
    __builtin_amdgcn_s_barrier();

    for (int t = 0; t < 32; ++t) {
        const int cur = t & 1;
        bf16x8 bfr[4][2];
#pragma unroll
        for (int ni = 0; ni < 4; ++ni)
#pragma unroll
            for (int kk = 0; kk < 2; ++kk)
                bfr[ni][kk] = *(const bf16x8*)&Bs[cur][wn * 64 + ni * 16 + r_][((kk * 4 + g_) ^ r7) * 8];

#pragma unroll
        for (int half = 0; half < 2; ++half) {
            bf16x8 afr[4][2];
#pragma unroll
            for (int mi = 0; mi < 4; ++mi)
#pragma unroll
                for (int kk = 0; kk < 2; ++kk)
                    afr[mi][kk] = *(const bf16x8*)&As[cur][wm * 128 + (half * 4 + mi) * 16 + r_][((kk * 4 + g_) ^ r7) * 8];
            __builtin_amdgcn_s_setprio(1);
#pragma unroll
            for (int kk = 0; kk < 2; ++kk)
#pragma unroll
                for (int ni = 0; ni < 4; ++ni)
#pragma unroll
                    for (int mi = 0; mi < 4; ++mi)
                        acc[half * 4 + mi][ni] = __builtin_amdgcn_mfma_f32_16x16x32_bf16(
                            afr[mi][kk], bfr[ni][kk], acc[half * 4 + mi][ni], 0, 0, 0);
            __builtin_amdgcn_s_setprio(0);
        }
        asm volatile("s_waitcnt lgkmcnt(0)" ::: "memory");
        __builtin_amdgcn_sched_barrier(0);
        __builtin_amdgcn_s_barrier();
        if (t + 2 < 32) {
            STAGE2(cur, t + 2);
            asm volatile("s_waitcnt vmcnt(8)" ::: "memory");
        } else {
            asm volatile("s_waitcnt vmcnt(0)" ::: "memory");
        }
        __builtin_amdgcn_sched_barrier(0);
        __builtin_amdgcn_s_barrier();
    }
#undef STAGE2

    float bias[4];
#pragma unroll
    for (int ni = 0; ni < 4; ++ni)
        bias[ni] = (ks == 0) ? b2[(size_t)e * C_DIM + n0 + wn * 64 + ni * 16 + r_] : 0.f;

    const int lg = lane >> 4;
#pragma unroll
    for (int mi = 0; mi < 8; ++mi) {
#pragma unroll
        for (int r = 0; r < 4; ++r) {
            const int m = wm * 128 + mi * 16 + lg * 4 + r;
            if (m0 + m < cnt) {
                const int   tk = tok[e * CAP + m0 + m];
                const float g  = gate[e * CAP + m0 + m];
#pragma unroll
                for (int ni = 0; ni < 4; ++ni) {
                    const int n = n0 + wn * 64 + ni * 16 + r_;
                    atomicAdd(&out[(size_t)tk * C_DIM + n], (acc[mi][ni][r] + bias[ni]) * g);
                }
            }
        }
    }
}

extern "C" void kernel_launch(void* const* d_in, const int* in_sizes, int n_in,
                              void* d_out, int out_size, void* d_ws, size_t ws_size,
                              hipStream_t stream) {
    const float* x  = (const float*)d_in[0];
    const float* rw = (const float*)d_in[1];
    const float* w1 = (const float*)d_in[2];
    const float* b1 = (const float*)d_in[3];
    const float* w2 = (const float*)d_in[4];
    const float* b2 = (const float*)d_in[5];
    float* out = (float*)d_out;

    char* ws = (char*)d_ws;
    size_t o = 0;
    bf16* xb     = (bf16*)(ws + o);  o += (size_t)N_TOK * C_DIM * sizeof(bf16);
    bf16* w1b    = (bf16*)(ws + o);  o += (size_t)N_EXP * H_DIM * C_DIM * sizeof(bf16);
    bf16* w2b    = (bf16*)(ws + o);  o += (size_t)N_EXP * C_DIM * H_DIM * sizeof(bf16);
    int*  tok    = (int*)(ws + o);   o += (size_t)N_EXP * CAP * sizeof(int);
    float* gate  = (float*)(ws + o); o += (size_t)N_EXP * CAP * sizeof(float);
    int*  counts = (int*)(ws + o);   o += 128;
    bf16* h      = (bf16*)(ws + o);  o += (size_t)(2 * N_TOK) * H_DIM * sizeof(bf16);

    hipMemsetAsync(d_out, 0, (size_t)N_TOK * C_DIM * sizeof(float), stream);
    hipMemsetAsync(counts, 0, 128, stream);

    cvt_all_k<<<dim3((unsigned)((NCVT + 255) / 256)), dim3(256), 0, stream>>>(x, w1, w2, xb, w1b, w2b);
    router_k<<<dim3(N_TOK / 16), dim3(1024), 0, stream>>>(x, rw, counts, tok, gate);
    fc1_k<<<dim3(16, 32, N_EXP), dim3(512), 0, stream>>>(xb, w1b, b1, counts, tok, h);
    fc2_k<<<dim3(4, 32, 2 * N_EXP), dim3(512), 0, stream>>>(h, w2b, b2, counts, tok, gate, out);
}